// Round 5
// baseline (338.090 us; speedup 1.0000x reference)
//
#include <hip/hip_runtime.h>

#define B_ 16
#define C_ 512
#define N_ 2048
#define D_ 64

typedef unsigned short u16;
typedef unsigned int   u32;
typedef __bf16 bfv4 __attribute__((ext_vector_type(4)));
typedef __bf16 bfv8 __attribute__((ext_vector_type(8)));
typedef float  f4   __attribute__((ext_vector_type(4)));
typedef float  f16v __attribute__((ext_vector_type(16)));

__device__ __forceinline__ u16 f2bf(float f) {
  u32 u = __float_as_uint(f);
  u32 r = (u + 0x7FFFu + ((u >> 16) & 1u)) >> 16;   // RNE
  return (u16)r;
}
__device__ __forceinline__ u32 pack2(float a, float b) {
  return (u32)f2bf(a) | ((u32)f2bf(b) << 16);
}
// 8-byte-aligned LDS load of 8 bf16 (2 x ds_read_b64)
__device__ __forceinline__ bfv8 ld8(const u16* p) {
  bfv4 lo = *(const bfv4*)p;
  bfv4 hi = *(const bfv4*)(p + 4);
  bfv8 r;
  r[0] = lo[0]; r[1] = lo[1]; r[2] = lo[2]; r[3] = lo[3];
  r[4] = hi[0]; r[5] = hi[1]; r[6] = hi[2]; r[7] = hi[3];
  return r;
}

// ---------------- all W -> bf16, one launch ----------------
__global__ __launch_bounds__(256) void conv_all(
    const float* __restrict__ Wq, const float* __restrict__ Wk,
    const float* __restrict__ Wv,
    u16* __restrict__ Wqb, u16* __restrict__ Wkb, u16* __restrict__ Wvb) {
  const int q4 = D_ * C_ / 4;   // 8192
  const int v4 = C_ * C_ / 4;   // 65536
  int i = blockIdx.x * 256 + threadIdx.x;
  const float* src; u16* dst; int j;
  if (i < q4)            { src = Wq; dst = Wqb; j = i; }
  else if (i < 2 * q4)   { src = Wk; dst = Wkb; j = i - q4; }
  else                   { j = i - 2 * q4; if (j >= v4) return; src = Wv; dst = Wvb; }
  float4 v = ((const float4*)src)[j];
  ((uint2*)dst)[j] = make_uint2(pack2(v.x, v.y), pack2(v.z, v.w));
}

// ---------------- fused transpose + Q/K/V projection v2 ----------------
#define XS_STR 516   // u16 row stride: 258 dwords -> 2-way bank pattern (free)
__global__ __launch_bounds__(256, 2) void proj_all(
    const float* __restrict__ x,
    const u16* __restrict__ Wqb, const u16* __restrict__ Wkb,
    const float* __restrict__ bq, const float* __restrict__ bk,
    const u16* __restrict__ Wvb, const float* __restrict__ bv,
    u16* __restrict__ Qb, u16* __restrict__ Kb, u16* __restrict__ Vb) {
  __shared__ u16 xs[64][XS_STR];    // [n][c]
  const int b = blockIdx.x, n0 = blockIdx.y * 64;
  const int t = threadIdx.x;
  const int w = t >> 6, lane = t & 63;
  const int l15 = lane & 15, quad = lane >> 4;
  const int l31 = lane & 31, h = lane >> 5;

  // ---- stage + transpose: 16 passes x (16 n-float4 x 16 c-pairs) ----
  {
    const int n4 = t & 15, cp = t >> 4;
#pragma unroll 2
    for (int p = 0; p < 16; p++) {
      int c = p * 32 + cp * 2;
      const size_t rb = ((size_t)(b * C_) + c) * N_ + n0 + n4 * 4;
      float4 a = *(const float4*)&x[rb];
      float4 bb = *(const float4*)&x[rb + N_];
      *(u32*)&xs[n4 * 4 + 0][c] = pack2(a.x, bb.x);
      *(u32*)&xs[n4 * 4 + 1][c] = pack2(a.y, bb.y);
      *(u32*)&xs[n4 * 4 + 2][c] = pack2(a.z, bb.z);
      *(u32*)&xs[n4 * 4 + 3][c] = pack2(a.w, bb.w);
    }
  }
  __syncthreads();

  // ---- Q/K: wave w owns d-rows w*16..+16; nt iterates the 4 n-subtiles ----
  {
    f4 accQ[4], accK[4];
#pragma unroll
    for (int nt = 0; nt < 4; nt++) { accQ[nt] = (f4)(0.0f); accK[nt] = (f4)(0.0f); }
    const u16* wqrow = &Wqb[(size_t)(w * 16 + l15) * C_];
    const u16* wkrow = &Wkb[(size_t)(w * 16 + l15) * C_];
    bfv8 aq = *(const bfv8*)&wqrow[quad * 8];
    bfv8 ak = *(const bfv8*)&wkrow[quad * 8];
    for (int kc = 0; kc < 16; kc++) {
      const int kn = (kc + 1) & 15;            // wrap: avoids OOB tail read
      bfv8 aqn = *(const bfv8*)&wqrow[kn * 32 + quad * 8];
      bfv8 akn = *(const bfv8*)&wkrow[kn * 32 + quad * 8];
#pragma unroll
      for (int nt = 0; nt < 4; nt++) {
        bfv8 bx = ld8(&xs[nt * 16 + l15][kc * 32 + quad * 8]);
        accQ[nt] = __builtin_amdgcn_mfma_f32_16x16x32_bf16(aq, bx, accQ[nt], 0, 0, 0);
        accK[nt] = __builtin_amdgcn_mfma_f32_16x16x32_bf16(ak, bx, accK[nt], 0, 0, 0);
      }
      aq = aqn; ak = akn;
    }
    f4 bq4 = *(const f4*)&bq[w * 16 + quad * 4];
    f4 bk4 = *(const f4*)&bk[w * 16 + quad * 4];
#pragma unroll
    for (int nt = 0; nt < 4; nt++) {
      const size_t orow = ((size_t)(b * N_) + n0 + nt * 16 + l15) * D_ + w * 16 + quad * 4;
      *(uint2*)&Qb[orow] =
          make_uint2(pack2(accQ[nt][0] + bq4[0], accQ[nt][1] + bq4[1]),
                     pack2(accQ[nt][2] + bq4[2], accQ[nt][3] + bq4[3]));
      *(uint2*)&Kb[orow] =
          make_uint2(pack2(accK[nt][0] + bk4[0], accK[nt][1] + bk4[1]),
                     pack2(accK[nt][2] + bk4[2], accK[nt][3] + bk4[3]));
    }
  }

  // ---- V: wave w owns c-range w*128; 2-deep Wv fragment pipeline ----
  {
    f16v acc[4][2];
#pragma unroll
    for (int mt = 0; mt < 4; mt++)
#pragma unroll
      for (int nt = 0; nt < 2; nt++) acc[mt][nt] = (f16v)(0.0f);
    const u16* wvrow[4];
#pragma unroll
    for (int mt = 0; mt < 4; mt++)
      wvrow[mt] = &Wvb[(size_t)(w * 128 + mt * 32 + l31) * C_ + h * 8];

    bfv8 acur[4], anxt[4];
#pragma unroll
    for (int mt = 0; mt < 4; mt++) acur[mt] = *(const bfv8*)&wvrow[mt][0];

    for (int kc2 = 0; kc2 < 16; kc2++) {
      {
        const int kc = 2 * kc2;
#pragma unroll
        for (int mt = 0; mt < 4; mt++)
          anxt[mt] = *(const bfv8*)&wvrow[mt][(kc + 1) * 16];
        bfv8 bx0 = ld8(&xs[l31][kc * 16 + h * 8]);
        bfv8 bx1 = ld8(&xs[32 + l31][kc * 16 + h * 8]);
#pragma unroll
        for (int mt = 0; mt < 4; mt++) {
          acc[mt][0] = __builtin_amdgcn_mfma_f32_32x32x16_bf16(acur[mt], bx0, acc[mt][0], 0, 0, 0);
          acc[mt][1] = __builtin_amdgcn_mfma_f32_32x32x16_bf16(acur[mt], bx1, acc[mt][1], 0, 0, 0);
        }
      }
      {
        const int kc = 2 * kc2 + 1;
        const int kn = (kc + 1) & 31;          // wrap: avoids OOB tail read
#pragma unroll
        for (int mt = 0; mt < 4; mt++)
          acur[mt] = *(const bfv8*)&wvrow[mt][kn * 16];
        bfv8 bx0 = ld8(&xs[l31][kc * 16 + h * 8]);
        bfv8 bx1 = ld8(&xs[32 + l31][kc * 16 + h * 8]);
#pragma unroll
        for (int mt = 0; mt < 4; mt++) {
          acc[mt][0] = __builtin_amdgcn_mfma_f32_32x32x16_bf16(anxt[mt], bx0, acc[mt][0], 0, 0, 0);
          acc[mt][1] = __builtin_amdgcn_mfma_f32_32x32x16_bf16(anxt[mt], bx1, acc[mt][1], 0, 0, 0);
        }
      }
    }
#pragma unroll
    for (int mt = 0; mt < 4; mt++)
#pragma unroll
      for (int nt = 0; nt < 2; nt++)
#pragma unroll
        for (int g = 0; g < 4; g++) {
          f4 bv4 = *(const f4*)&bv[w * 128 + mt * 32 + g * 8 + h * 4];
#pragma unroll
          for (int r = 0; r < 4; r++) {
            int c = w * 128 + mt * 32 + g * 8 + h * 4 + r;
            Vb[((size_t)(b * C_) + c) * N_ + n0 + nt * 32 + l31] =
                f2bf(acc[mt][nt][g * 4 + r] + bv4[r]);
          }
        }
  }
}

// ---------------- fused attention v4 ----------------
// Grid (B, N/128, 4): block = 128 i x 128 c, 4 waves.
// Per-wave acc shrinks to acc[2][2] (64 regs) -> total ~164 regs/wave ->
// 3 waves/SIMD via __launch_bounds__(256,3). i_tile stays 128 so V re-read
// multiplier (16x) and FETCH are unchanged vs round-2 (round-3 lesson).
// Vs: one 64c x 64j tile per wave PAIR, staged cooperatively (4
// global_load_lds per wave, XOR chunk swizzle on global source).
// Ps single-buffered; 2 barriers/iter: E -> bar1 -> PV -> bar2 -> stage.
// bar2 makes the partner-wave's stage safe (pair-shared Vs).
// LDS ~33.5 KB -> 3 blocks/CU (12 waves/CU, waves from 3 different
// blocks per SIMD -> barrier-decoupled latency cover).
// Ps packing uses native (__bf16) casts (v_cvt_pk_bf16_f32, RNE) instead
// of the ~11-op manual RNE pack2 -> E-phase VALU ~2x smaller.
#define PS_STR 68   // u16: 34 dwords -> 2-way bank pattern (free)

__device__ __forceinline__ void stage_v_half(const u16* p0, u16* vsw, int j0, int sh) {
#pragma unroll
  for (int s = 0; s < 4; s++) {
    const int ss = sh + s;
    __builtin_amdgcn_global_load_lds(
        (const __attribute__((address_space(1))) void*)(p0 + (size_t)ss * 8 * N_ + j0),
        (__attribute__((address_space(3))) void*)(vsw + ss * 512),
        16, 0, 0);
  }
}

__global__ __launch_bounds__(256, 3) void attn(
    const float* __restrict__ x, const u16* __restrict__ Qb,
    const u16* __restrict__ Kb, const u16* __restrict__ Vb,
    const float* __restrict__ gamma, float* __restrict__ out) {
  __shared__ u16 Vs[2][64][64];        // [wavepair][c_local][j] 16 KB
  __shared__ u16 Ps[128][PS_STR];      // 17.4 KB, single-buffered
  __shared__ float invl[128];
  const int b = blockIdx.x, i0 = blockIdx.y * 128, ch = blockIdx.z;
  const int t = threadIdx.x, w = t >> 6, lane = t & 63;
  const int l15 = lane & 15, quad = lane >> 4;
  const int l31 = lane & 31, h = lane >> 5;
  const int wp = w >> 1, wh = w & 1;

  // V staging: lane = sr*8 + sx; LDS[row][x] = G[row][x ^ (row&7)]
  const int sr = lane >> 3;            // row within 8-row group
  const int sx = lane & 7;             // chunk slot
  const int cbase = ch * 128 + wp * 64;
  const u16* p0 = &Vb[((size_t)(b * C_) + cbase + sr) * N_ + ((sx ^ sr) << 3)];
  u16* vsw = &Vs[wp][0][0];

  stage_v_half(p0, vsw, 0, wh * 4);    // prefetch first V tile (async, half/wave)

  bfv8 qf[2][2];                       // [isub][kc] : E i-cols w*32..+32
#pragma unroll
  for (int isub = 0; isub < 2; isub++)
#pragma unroll
    for (int kc = 0; kc < 2; kc++)
      qf[isub][kc] = *(const bfv8*)&Qb[((size_t)(b * N_) + i0 + w * 32 + isub * 16 + l15) * D_ +
                                       kc * 32 + quad * 8];

  f16v acc[2][2];   // mt: i = wh*64 + mt*32.., nt: c = cbase + nt*32..
#pragma unroll
  for (int mt = 0; mt < 2; mt++)
#pragma unroll
    for (int nt = 0; nt < 2; nt++) acc[mt][nt] = (f16v)(0.0f);
  float la0 = 0.0f, la1 = 0.0f;
  const int swz = l31 & 7;

  for (int j0 = 0; j0 < N_; j0 += 64) {
    // ---- E^T: wave w computes cols i = w*32..+32 (2 subtiles), all 64 j ----
#pragma unroll
    for (int jt = 0; jt < 4; jt++) {
      const u16* krow = &Kb[((size_t)(b * N_) + j0 + jt * 16 + l15) * D_];
      bfv8 kf0 = *(const bfv8*)&krow[quad * 8];
      bfv8 kf1 = *(const bfv8*)&krow[32 + quad * 8];
      f4 e0 = (f4)(0.0f), e1 = (f4)(0.0f);
      e0 = __builtin_amdgcn_mfma_f32_16x16x32_bf16(kf0, qf[0][0], e0, 0, 0, 0);
      e0 = __builtin_amdgcn_mfma_f32_16x16x32_bf16(kf1, qf[0][1], e0, 0, 0, 0);
      e1 = __builtin_amdgcn_mfma_f32_16x16x32_bf16(kf0, qf[1][0], e1, 0, 0, 0);
      e1 = __builtin_amdgcn_mfma_f32_16x16x32_bf16(kf1, qf[1][1], e1, 0, 0, 0);
      {
        float p0_ = __expf(e0[0]), p1_ = __expf(e0[1]);
        float p2_ = __expf(e0[2]), p3_ = __expf(e0[3]);
        la0 += (p0_ + p1_) + (p2_ + p3_);
        bfv4 pk;
        pk[0] = (__bf16)p0_; pk[1] = (__bf16)p1_;
        pk[2] = (__bf16)p2_; pk[3] = (__bf16)p3_;
        *(bfv4*)&Ps[w * 32 + l15][jt * 16 + quad * 4] = pk;
      }
      {
        float p0_ = __expf(e1[0]), p1_ = __expf(e1[1]);
        float p2_ = __expf(e1[2]), p3_ = __expf(e1[3]);
        la1 += (p0_ + p1_) + (p2_ + p3_);
        bfv4 pk;
        pk[0] = (__bf16)p0_; pk[1] = (__bf16)p1_;
        pk[2] = (__bf16)p2_; pk[3] = (__bf16)p3_;
        *(bfv4*)&Ps[w * 32 + 16 + l15][jt * 16 + quad * 4] = pk;
      }
    }
    __syncthreads();   // bar1: Ps ready; each wave's V stage drained -> Vs ready

    // ---- PV: A = P (LDS, own 64-i half), B = V (LDS, pair's 64-c slice) ----
    __builtin_amdgcn_s_setprio(1);
#pragma unroll
    for (int kc = 0; kc < 4; kc++) {
      bfv8 pa[2];
#pragma unroll
      for (int mt = 0; mt < 2; mt++)
        pa[mt] = ld8(&Ps[wh * 64 + mt * 32 + l31][kc * 16 + h * 8]);
      bfv8 vb[2];
#pragma unroll
      for (int nt = 0; nt < 2; nt++)
        vb[nt] = *(const bfv8*)&vsw[(nt * 32 + l31) * 64 + (((kc * 2 + h) ^ swz) << 3)];
#pragma unroll
      for (int mt = 0; mt < 2; mt++)
#pragma unroll
        for (int nt = 0; nt < 2; nt++)
          acc[mt][nt] = __builtin_amdgcn_mfma_f32_32x32x16_bf16(pa[mt], vb[nt], acc[mt][nt], 0, 0, 0);
    }
    __builtin_amdgcn_s_setprio(0);
    __syncthreads();   // bar2: PV done reading Ps & Vs -> safe to overwrite
    if (j0 + 64 < N_) stage_v_half(p0, vsw, j0 + 64, wh * 4);
  }

  la0 += __shfl_xor(la0, 16, 64);
  la0 += __shfl_xor(la0, 32, 64);
  la1 += __shfl_xor(la1, 16, 64);
  la1 += __shfl_xor(la1, 32, 64);
  if (lane < 16) {
    invl[w * 32 + l15]      = 1.0f / la0;
    invl[w * 32 + 16 + l15] = 1.0f / la1;
  }
  __syncthreads();

  const float gam = gamma[0];
#pragma unroll
  for (int mt = 0; mt < 2; mt++)
#pragma unroll
    for (int nt = 0; nt < 2; nt++) {
      int c = cbase + nt * 32 + l31;
#pragma unroll
      for (int g = 0; g < 4; g++) {
        int ib = wh * 64 + mt * 32 + g * 8 + h * 4;
        f4 il = *(const f4*)&invl[ib];
        size_t off = ((size_t)(b * C_) + c) * N_ + i0 + ib;
        f4 xv = *(const f4*)&x[off];
        f4 o;
#pragma unroll
        for (int r = 0; r < 4; r++)
          o[r] = xv[r] + gam * acc[mt][nt][g * 4 + r] * il[r];
        *(f4*)&out[off] = o;
      }
    }
}

extern "C" void kernel_launch(void* const* d_in, const int* in_sizes, int n_in,
                              void* d_out, int out_size, void* d_ws, size_t ws_size,
                              hipStream_t stream) {
  const float* x     = (const float*)d_in[0];
  const float* Wq    = (const float*)d_in[1];
  const float* bq    = (const float*)d_in[2];
  const float* Wk    = (const float*)d_in[3];
  const float* bk    = (const float*)d_in[4];
  const float* Wv    = (const float*)d_in[5];
  const float* bv    = (const float*)d_in[6];
  const float* gamma = (const float*)d_in[7];
  float* out = (float*)d_out;

  u16* wsu = (u16*)d_ws;
  u16* Qb  = wsu;                                   // B*N*D
  u16* Kb  = Qb  + (size_t)B_ * N_ * D_;            // B*N*D
  u16* Vb  = Kb  + (size_t)B_ * N_ * D_;            // B*C*N
  u16* Wqb = Vb  + (size_t)B_ * C_ * N_;            // D*C
  u16* Wkb = Wqb + (size_t)D_ * C_;                 // D*C
  u16* Wvb = Wkb + (size_t)D_ * C_;                 // C*C

  conv_all<<<dim3(320), 256, 0, stream>>>(Wq, Wk, Wv, Wqb, Wkb, Wvb);
  proj_all<<<dim3(B_, N_ / 64), 256, 0, stream>>>(x, Wqb, Wkb, bq, bk, Wvb, bv, Qb, Kb, Vb);
  attn<<<dim3(B_, N_ / 128, 4), 256, 0, stream>>>(x, Qb, Kb, Vb, gamma, out);
}

// Round 6
// 262.830 us; speedup vs baseline: 1.2863x; 1.2863x over previous
//
#include <hip/hip_runtime.h>

#define B_ 16
#define C_ 512
#define N_ 2048
#define D_ 64

typedef unsigned short u16;
typedef unsigned int   u32;
typedef __bf16 bfv2 __attribute__((ext_vector_type(2)));
typedef __bf16 bfv4 __attribute__((ext_vector_type(4)));
typedef __bf16 bfv8 __attribute__((ext_vector_type(8)));
typedef float  f4   __attribute__((ext_vector_type(4)));
typedef float  f16v __attribute__((ext_vector_type(16)));

// 8-byte-aligned LDS load of 8 bf16 (2 x ds_read_b64)
__device__ __forceinline__ bfv8 ld8(const u16* p) {
  bfv4 lo = *(const bfv4*)p;
  bfv4 hi = *(const bfv4*)(p + 4);
  bfv8 r;
  r[0] = lo[0]; r[1] = lo[1]; r[2] = lo[2]; r[3] = lo[3];
  r[4] = hi[0]; r[5] = hi[1]; r[6] = hi[2]; r[7] = hi[3];
  return r;
}

// ---------------- all W -> bf16, one launch ----------------
__global__ __launch_bounds__(256) void conv_all(
    const float* __restrict__ Wq, const float* __restrict__ Wk,
    const float* __restrict__ Wv,
    u16* __restrict__ Wqb, u16* __restrict__ Wkb, u16* __restrict__ Wvb) {
  const int q4 = D_ * C_ / 4;   // 8192
  const int v4 = C_ * C_ / 4;   // 65536
  int i = blockIdx.x * 256 + threadIdx.x;
  const float* src; u16* dst; int j;
  if (i < q4)            { src = Wq; dst = Wqb; j = i; }
  else if (i < 2 * q4)   { src = Wk; dst = Wkb; j = i - q4; }
  else                   { j = i - 2 * q4; if (j >= v4) return; src = Wv; dst = Wvb; }
  float4 v = ((const float4*)src)[j];
  bfv4 o;
  o[0] = (__bf16)v.x; o[1] = (__bf16)v.y;
  o[2] = (__bf16)v.z; o[3] = (__bf16)v.w;
  *(bfv4*)&dst[j * 4] = o;
}

// ---------------- fused transpose + Q/K/V projection v2.1 ----------------
// (round-4 structure; native bf16 casts replace manual RNE pack; staging
//  unrolled 4 so more x loads are in flight)
#define XS_STR 516   // u16 row stride: 258 dwords -> 2-way bank pattern (free)
__global__ __launch_bounds__(256, 2) void proj_all(
    const float* __restrict__ x,
    const u16* __restrict__ Wqb, const u16* __restrict__ Wkb,
    const float* __restrict__ bq, const float* __restrict__ bk,
    const u16* __restrict__ Wvb, const float* __restrict__ bv,
    u16* __restrict__ Qb, u16* __restrict__ Kb, u16* __restrict__ Vb) {
  __shared__ u16 xs[64][XS_STR];    // [n][c]
  const int b = blockIdx.x, n0 = blockIdx.y * 64;
  const int t = threadIdx.x;
  const int w = t >> 6, lane = t & 63;
  const int l15 = lane & 15, quad = lane >> 4;
  const int l31 = lane & 31, h = lane >> 5;

  // ---- stage + transpose: 16 passes x (16 n-float4 x 16 c-pairs) ----
  {
    const int n4 = t & 15, cp = t >> 4;
#pragma unroll 4
    for (int p = 0; p < 16; p++) {
      int c = p * 32 + cp * 2;
      const size_t rb = ((size_t)(b * C_) + c) * N_ + n0 + n4 * 4;
      float4 a = *(const float4*)&x[rb];
      float4 bb = *(const float4*)&x[rb + N_];
      bfv2 w0, w1, w2, w3;
      w0[0] = (__bf16)a.x; w0[1] = (__bf16)bb.x;
      w1[0] = (__bf16)a.y; w1[1] = (__bf16)bb.y;
      w2[0] = (__bf16)a.z; w2[1] = (__bf16)bb.z;
      w3[0] = (__bf16)a.w; w3[1] = (__bf16)bb.w;
      *(bfv2*)&xs[n4 * 4 + 0][c] = w0;
      *(bfv2*)&xs[n4 * 4 + 1][c] = w1;
      *(bfv2*)&xs[n4 * 4 + 2][c] = w2;
      *(bfv2*)&xs[n4 * 4 + 3][c] = w3;
    }
  }
  __syncthreads();

  // ---- Q/K: wave w owns d-rows w*16..+16; nt iterates the 4 n-subtiles ----
  {
    f4 accQ[4], accK[4];
#pragma unroll
    for (int nt = 0; nt < 4; nt++) { accQ[nt] = (f4)(0.0f); accK[nt] = (f4)(0.0f); }
    const u16* wqrow = &Wqb[(size_t)(w * 16 + l15) * C_];
    const u16* wkrow = &Wkb[(size_t)(w * 16 + l15) * C_];
    bfv8 aq = *(const bfv8*)&wqrow[quad * 8];
    bfv8 ak = *(const bfv8*)&wkrow[quad * 8];
    for (int kc = 0; kc < 16; kc++) {
      const int kn = (kc + 1) & 15;            // wrap: avoids OOB tail read
      bfv8 aqn = *(const bfv8*)&wqrow[kn * 32 + quad * 8];
      bfv8 akn = *(const bfv8*)&wkrow[kn * 32 + quad * 8];
#pragma unroll
      for (int nt = 0; nt < 4; nt++) {
        bfv8 bx = ld8(&xs[nt * 16 + l15][kc * 32 + quad * 8]);
        accQ[nt] = __builtin_amdgcn_mfma_f32_16x16x32_bf16(aq, bx, accQ[nt], 0, 0, 0);
        accK[nt] = __builtin_amdgcn_mfma_f32_16x16x32_bf16(ak, bx, accK[nt], 0, 0, 0);
      }
      aq = aqn; ak = akn;
    }
    f4 bq4 = *(const f4*)&bq[w * 16 + quad * 4];
    f4 bk4 = *(const f4*)&bk[w * 16 + quad * 4];
#pragma unroll
    for (int nt = 0; nt < 4; nt++) {
      const size_t orow = ((size_t)(b * N_) + n0 + nt * 16 + l15) * D_ + w * 16 + quad * 4;
      bfv4 pq, pk;
#pragma unroll
      for (int r = 0; r < 4; r++) {
        pq[r] = (__bf16)(accQ[nt][r] + bq4[r]);
        pk[r] = (__bf16)(accK[nt][r] + bk4[r]);
      }
      *(bfv4*)&Qb[orow] = pq;
      *(bfv4*)&Kb[orow] = pk;
    }
  }

  // ---- V: wave w owns c-range w*128; 2-deep Wv fragment pipeline ----
  {
    f16v acc[4][2];
#pragma unroll
    for (int mt = 0; mt < 4; mt++)
#pragma unroll
      for (int nt = 0; nt < 2; nt++) acc[mt][nt] = (f16v)(0.0f);
    const u16* wvrow[4];
#pragma unroll
    for (int mt = 0; mt < 4; mt++)
      wvrow[mt] = &Wvb[(size_t)(w * 128 + mt * 32 + l31) * C_ + h * 8];

    bfv8 acur[4], anxt[4];
#pragma unroll
    for (int mt = 0; mt < 4; mt++) acur[mt] = *(const bfv8*)&wvrow[mt][0];

    for (int kc2 = 0; kc2 < 16; kc2++) {
      {
        const int kc = 2 * kc2;
#pragma unroll
        for (int mt = 0; mt < 4; mt++)
          anxt[mt] = *(const bfv8*)&wvrow[mt][(kc + 1) * 16];
        bfv8 bx0 = ld8(&xs[l31][kc * 16 + h * 8]);
        bfv8 bx1 = ld8(&xs[32 + l31][kc * 16 + h * 8]);
#pragma unroll
        for (int mt = 0; mt < 4; mt++) {
          acc[mt][0] = __builtin_amdgcn_mfma_f32_32x32x16_bf16(acur[mt], bx0, acc[mt][0], 0, 0, 0);
          acc[mt][1] = __builtin_amdgcn_mfma_f32_32x32x16_bf16(acur[mt], bx1, acc[mt][1], 0, 0, 0);
        }
      }
      {
        const int kc = 2 * kc2 + 1;
        const int kn = (kc + 1) & 31;          // wrap: avoids OOB tail read
#pragma unroll
        for (int mt = 0; mt < 4; mt++)
          acur[mt] = *(const bfv8*)&wvrow[mt][kn * 16];
        bfv8 bx0 = ld8(&xs[l31][kc * 16 + h * 8]);
        bfv8 bx1 = ld8(&xs[32 + l31][kc * 16 + h * 8]);
#pragma unroll
        for (int mt = 0; mt < 4; mt++) {
          acc[mt][0] = __builtin_amdgcn_mfma_f32_32x32x16_bf16(anxt[mt], bx0, acc[mt][0], 0, 0, 0);
          acc[mt][1] = __builtin_amdgcn_mfma_f32_32x32x16_bf16(anxt[mt], bx1, acc[mt][1], 0, 0, 0);
        }
      }
    }
#pragma unroll
    for (int mt = 0; mt < 4; mt++)
#pragma unroll
      for (int nt = 0; nt < 2; nt++)
#pragma unroll
        for (int g = 0; g < 4; g++) {
          f4 bv4 = *(const f4*)&bv[w * 128 + mt * 32 + g * 8 + h * 4];
#pragma unroll
          for (int r = 0; r < 4; r++) {
            int c = w * 128 + mt * 32 + g * 8 + h * 4 + r;
            *(__bf16*)&Vb[((size_t)(b * C_) + c) * N_ + n0 + nt * 32 + l31] =
                (__bf16)(acc[mt][nt][g * 4 + r] + bv4[r]);
          }
        }
  }
}

// ---------------- fused attention v2.1 (v2 structure, 136 us proven) -------
// Grid (B, N/128, 2): block = 128 i-rows x 256 c-cols. V staged per-wave via
// global_load_lds with XOR chunk swizzle on the global source. Only change
// vs v2: Ps packing uses native (__bf16) casts (v_cvt_pk_bf16_f32, same RNE)
// instead of the ~11-op manual pack2 -> E-phase VALU ~2x smaller.
#define PS_STR 68   // u16: 34 dwords -> 2-way bank pattern (free)

__device__ __forceinline__ void stage_v(const u16* p0, u16* vsw, int j0) {
#pragma unroll
  for (int s = 0; s < 8; s++) {
    __builtin_amdgcn_global_load_lds(
        (const __attribute__((address_space(1))) void*)(p0 + (size_t)s * 8 * N_ + j0),
        (__attribute__((address_space(3))) void*)(vsw + s * 512),
        16, 0, 0);
  }
}

__global__ __launch_bounds__(256, 2) void attn(
    const float* __restrict__ x, const u16* __restrict__ Qb,
    const u16* __restrict__ Kb, const u16* __restrict__ Vb,
    const float* __restrict__ gamma, float* __restrict__ out) {
  __shared__ u16 Vs[4][64][64];        // [wave][c_local][j], swizzled chunks
  __shared__ u16 Ps[2][128][PS_STR];   // [buf][i][j]
  __shared__ float invl[128];
  const int b = blockIdx.x, i0 = blockIdx.y * 128, ch = blockIdx.z;
  const int t = threadIdx.x, w = t >> 6, lane = t & 63;
  const int l15 = lane & 15, quad = lane >> 4;
  const int l31 = lane & 31, h = lane >> 5;

  // V staging geometry: lane = r*8 + xchunk; LDS[row][x] = G[row][x ^ (row&7)]
  const int sr = lane >> 3;            // row within 8-row group
  const int sx = lane & 7;             // chunk slot
  const int cbase = ch * 256 + w * 64; // this wave's c-slice
  const u16* p0 = &Vb[((size_t)(b * C_) + cbase + sr) * N_ + ((sx ^ sr) << 3)];
  u16* vsw = &Vs[w][0][0];

  stage_v(p0, vsw, 0);                 // prefetch first V tile (async)

  bfv8 qf[2][2];                       // [isub][kc]
#pragma unroll
  for (int isub = 0; isub < 2; isub++)
#pragma unroll
    for (int kc = 0; kc < 2; kc++)
      qf[isub][kc] = *(const bfv8*)&Qb[((size_t)(b * N_) + i0 + w * 32 + isub * 16 + l15) * D_ +
                                       kc * 32 + quad * 8];

  f16v acc[4][2];   // mt: i = mt*32.., nt: c = cbase + nt*32..
#pragma unroll
  for (int mt = 0; mt < 4; mt++)
#pragma unroll
    for (int nt = 0; nt < 2; nt++) acc[mt][nt] = (f16v)(0.0f);
  float la0 = 0.0f, la1 = 0.0f;
  const int swz = l31 & 7;

  int buf = 0;
  for (int j0 = 0; j0 < N_; j0 += 64, buf ^= 1) {
    // ---- E^T: wave w computes cols i = w*32..+32 (2 subtiles), all 64 j ----
#pragma unroll
    for (int jt = 0; jt < 4; jt++) {
      const u16* krow = &Kb[((size_t)(b * N_) + j0 + jt * 16 + l15) * D_];
      bfv8 kf0 = *(const bfv8*)&krow[quad * 8];
      bfv8 kf1 = *(const bfv8*)&krow[32 + quad * 8];
      f4 e0 = (f4)(0.0f), e1 = (f4)(0.0f);
      e0 = __builtin_amdgcn_mfma_f32_16x16x32_bf16(kf0, qf[0][0], e0, 0, 0, 0);
      e0 = __builtin_amdgcn_mfma_f32_16x16x32_bf16(kf1, qf[0][1], e0, 0, 0, 0);
      e1 = __builtin_amdgcn_mfma_f32_16x16x32_bf16(kf0, qf[1][0], e1, 0, 0, 0);
      e1 = __builtin_amdgcn_mfma_f32_16x16x32_bf16(kf1, qf[1][1], e1, 0, 0, 0);
      {
        float p0_ = __expf(e0[0]), p1_ = __expf(e0[1]);
        float p2_ = __expf(e0[2]), p3_ = __expf(e0[3]);
        la0 += (p0_ + p1_) + (p2_ + p3_);
        bfv4 pk;
        pk[0] = (__bf16)p0_; pk[1] = (__bf16)p1_;
        pk[2] = (__bf16)p2_; pk[3] = (__bf16)p3_;
        *(bfv4*)&Ps[buf][w * 32 + l15][jt * 16 + quad * 4] = pk;
      }
      {
        float p0_ = __expf(e1[0]), p1_ = __expf(e1[1]);
        float p2_ = __expf(e1[2]), p3_ = __expf(e1[3]);
        la1 += (p0_ + p1_) + (p2_ + p3_);
        bfv4 pk;
        pk[0] = (__bf16)p0_; pk[1] = (__bf16)p1_;
        pk[2] = (__bf16)p2_; pk[3] = (__bf16)p3_;
        *(bfv4*)&Ps[buf][w * 32 + 16 + l15][jt * 16 + quad * 4] = pk;
      }
    }
    // barrier: Ps[buf] published; implicit vmcnt(0) drain completes V stage
    __syncthreads();

    // ---- PV: A = P (LDS, all 128 i), B = V (LDS, own 64-c slice) ----
    __builtin_amdgcn_s_setprio(1);
#pragma unroll
    for (int kc = 0; kc < 4; kc++) {
      bfv8 pa[4];
#pragma unroll
      for (int mt = 0; mt < 4; mt++)
        pa[mt] = ld8(&Ps[buf][mt * 32 + l31][kc * 16 + h * 8]);
      bfv8 vb[2];
#pragma unroll
      for (int nt = 0; nt < 2; nt++)
        vb[nt] = *(const bfv8*)&vsw[(nt * 32 + l31) * 64 + (((kc * 2 + h) ^ swz) << 3)];
#pragma unroll
      for (int mt = 0; mt < 4; mt++)
#pragma unroll
        for (int nt = 0; nt < 2; nt++)
          acc[mt][nt] = __builtin_amdgcn_mfma_f32_32x32x16_bf16(pa[mt], vb[nt], acc[mt][nt], 0, 0, 0);
    }
    __builtin_amdgcn_s_setprio(0);
    // pin: stage must not be hoisted above the Vs ds_reads it overwrites
    __builtin_amdgcn_sched_barrier(0);
    if (j0 + 64 < N_) stage_v(p0, vsw, j0 + 64);   // async prefetch next tile
  }

  la0 += __shfl_xor(la0, 16, 64);
  la0 += __shfl_xor(la0, 32, 64);
  la1 += __shfl_xor(la1, 16, 64);
  la1 += __shfl_xor(la1, 32, 64);
  if (lane < 16) {
    invl[w * 32 + l15]      = 1.0f / la0;
    invl[w * 32 + 16 + l15] = 1.0f / la1;
  }
  __syncthreads();

  const float gam = gamma[0];
#pragma unroll
  for (int mt = 0; mt < 4; mt++)
#pragma unroll
    for (int nt = 0; nt < 2; nt++) {
      int c = cbase + nt * 32 + l31;
#pragma unroll
      for (int g = 0; g < 4; g++) {
        int ib = mt * 32 + g * 8 + h * 4;
        f4 il = *(const f4*)&invl[ib];
        size_t off = ((size_t)(b * C_) + c) * N_ + i0 + ib;
        f4 xv = *(const f4*)&x[off];
        f4 o;
#pragma unroll
        for (int r = 0; r < 4; r++)
          o[r] = xv[r] + gam * acc[mt][nt][g * 4 + r] * il[r];
        *(f4*)&out[off] = o;
      }
    }
}

extern "C" void kernel_launch(void* const* d_in, const int* in_sizes, int n_in,
                              void* d_out, int out_size, void* d_ws, size_t ws_size,
                              hipStream_t stream) {
  const float* x     = (const float*)d_in[0];
  const float* Wq    = (const float*)d_in[1];
  const float* bq    = (const float*)d_in[2];
  const float* Wk    = (const float*)d_in[3];
  const float* bk    = (const float*)d_in[4];
  const float* Wv    = (const float*)d_in[5];
  const float* bv    = (const float*)d_in[6];
  const float* gamma = (const float*)d_in[7];
  float* out = (float*)d_out;

  u16* wsu = (u16*)d_ws;
  u16* Qb  = wsu;                                   // B*N*D
  u16* Kb  = Qb  + (size_t)B_ * N_ * D_;            // B*N*D
  u16* Vb  = Kb  + (size_t)B_ * N_ * D_;            // B*C*N
  u16* Wqb = Vb  + (size_t)B_ * C_ * N_;            // D*C
  u16* Wkb = Wqb + (size_t)D_ * C_;                 // D*C
  u16* Wvb = Wkb + (size_t)D_ * C_;                 // C*C

  conv_all<<<dim3(320), 256, 0, stream>>>(Wq, Wk, Wv, Wqb, Wkb, Wvb);
  proj_all<<<dim3(B_, N_ / 64), 256, 0, stream>>>(x, Wqb, Wkb, bq, bk, Wvb, bv, Qb, Kb, Vb);
  attn<<<dim3(B_, N_ / 128, 2), 256, 0, stream>>>(x, Qb, Kb, Vb, gamma, out);
}

// Round 8
// 254.565 us; speedup vs baseline: 1.3281x; 1.0325x over previous
//
#include <hip/hip_runtime.h>

#define B_ 16
#define C_ 512
#define N_ 2048
#define D_ 64

typedef unsigned short u16;
typedef unsigned int   u32;
typedef __bf16 bfv2 __attribute__((ext_vector_type(2)));
typedef __bf16 bfv4 __attribute__((ext_vector_type(4)));
typedef __bf16 bfv8 __attribute__((ext_vector_type(8)));
typedef float  f4   __attribute__((ext_vector_type(4)));
typedef float  f16v __attribute__((ext_vector_type(16)));

// 8-byte-aligned LDS load of 8 bf16 (2 x ds_read_b64)
__device__ __forceinline__ bfv8 ld8(const u16* p) {
  bfv4 lo = *(const bfv4*)p;
  bfv4 hi = *(const bfv4*)(p + 4);
  bfv8 r;
  r[0] = lo[0]; r[1] = lo[1]; r[2] = lo[2]; r[3] = lo[3];
  r[4] = hi[0]; r[5] = hi[1]; r[6] = hi[2]; r[7] = hi[3];
  return r;
}

// ---------------- all W -> bf16 + K-PANEL layout, one launch ----------------
// Wq/Wk: element (d, c) -> Wqp[((c>>5)*64 + d)*32 + (c&31)]
//   so the 16x16x32 A-frag load (lane: d=l15, k=quad*8) is a coalesced
//   1 KB stream: addr = kc*2048*2B + d*64B + quad*16B.
// Wv: element (m, c) -> Wvp[((c>>4)*512 + m)*16 + (c&15)]
//   so the 32x32x16 A-frag load (lane: m=l31, k=h*8) is coalesced:
//   addr = kc*8192*2B + m*32B + h*16B.
__global__ __launch_bounds__(256) void conv_all(
    const float* __restrict__ Wq, const float* __restrict__ Wk,
    const float* __restrict__ Wv,
    u16* __restrict__ Wqb, u16* __restrict__ Wkb, u16* __restrict__ Wvb) {
  const int q4 = D_ * C_ / 4;   // 8192
  const int v4 = C_ * C_ / 4;   // 65536
  int i = blockIdx.x * 256 + threadIdx.x;
  const float* src; u16* dst; int j; int isv;
  if (i < q4)            { src = Wq; dst = Wqb; j = i; isv = 0; }
  else if (i < 2 * q4)   { src = Wk; dst = Wkb; j = i - q4; isv = 0; }
  else                   { j = i - 2 * q4; if (j >= v4) return; src = Wv; dst = Wvb; isv = 1; }
  float4 v = ((const float4*)src)[j];
  bfv4 o;
  o[0] = (__bf16)v.x; o[1] = (__bf16)v.y;
  o[2] = (__bf16)v.z; o[3] = (__bf16)v.w;
  size_t d;
  if (isv) {
    const int m = j >> 7, ci = (j & 127) * 4;          // Wv: 512 rows, C=512
    d = ((size_t)(ci >> 4) * 512 + m) * 16 + (ci & 15);
  } else {
    const int dd = j >> 7, ci = (j & 127) * 4;         // Wq/Wk: 64 rows, C=512
    d = ((size_t)(ci >> 5) * 64 + dd) * 32 + (ci & 31);
  }
  *(bfv4*)&dst[d] = o;
}

// ---------------- fused transpose + Q/K/V projection v3 ----------------
// v2.1 structure; weight loads switched to K-panel layout (coalesced
// A-fragment streams instead of 1KB-strided scatters).
#define XS_STR 516   // u16 row stride: 258 dwords -> 2-way bank pattern (free)
__global__ __launch_bounds__(256, 2) void proj_all(
    const float* __restrict__ x,
    const u16* __restrict__ Wqb, const u16* __restrict__ Wkb,
    const float* __restrict__ bq, const float* __restrict__ bk,
    const u16* __restrict__ Wvb, const float* __restrict__ bv,
    u16* __restrict__ Qb, u16* __restrict__ Kb, u16* __restrict__ Vb) {
  __shared__ u16 xs[64][XS_STR];    // [n][c]
  const int b = blockIdx.x, n0 = blockIdx.y * 64;
  const int t = threadIdx.x;
  const int w = t >> 6, lane = t & 63;
  const int l15 = lane & 15, quad = lane >> 4;
  const int l31 = lane & 31, h = lane >> 5;

  // ---- stage + transpose: 16 passes x (16 n-float4 x 16 c-pairs) ----
  {
    const int n4 = t & 15, cp = t >> 4;
#pragma unroll 4
    for (int p = 0; p < 16; p++) {
      int c = p * 32 + cp * 2;
      const size_t rb = ((size_t)(b * C_) + c) * N_ + n0 + n4 * 4;
      float4 a = *(const float4*)&x[rb];
      float4 bb = *(const float4*)&x[rb + N_];
      bfv2 w0, w1, w2, w3;
      w0[0] = (__bf16)a.x; w0[1] = (__bf16)bb.x;
      w1[0] = (__bf16)a.y; w1[1] = (__bf16)bb.y;
      w2[0] = (__bf16)a.z; w2[1] = (__bf16)bb.z;
      w3[0] = (__bf16)a.w; w3[1] = (__bf16)bb.w;
      *(bfv2*)&xs[n4 * 4 + 0][c] = w0;
      *(bfv2*)&xs[n4 * 4 + 1][c] = w1;
      *(bfv2*)&xs[n4 * 4 + 2][c] = w2;
      *(bfv2*)&xs[n4 * 4 + 3][c] = w3;
    }
  }
  __syncthreads();

  // ---- Q/K: wave w owns d-rows w*16..+16; nt iterates the 4 n-subtiles ----
  {
    f4 accQ[4], accK[4];
#pragma unroll
    for (int nt = 0; nt < 4; nt++) { accQ[nt] = (f4)(0.0f); accK[nt] = (f4)(0.0f); }
    // panel base: elem (kc*64 + d)*32 + quad*8, d = w*16+l15
    const u16* wqp = &Wqb[(size_t)(w * 16 + l15) * 32 + quad * 8];
    const u16* wkp = &Wkb[(size_t)(w * 16 + l15) * 32 + quad * 8];
    bfv8 aq = *(const bfv8*)&wqp[0];
    bfv8 ak = *(const bfv8*)&wkp[0];
    for (int kc = 0; kc < 16; kc++) {
      const int kn = (kc + 1) & 15;            // wrap: avoids OOB tail read
      bfv8 aqn = *(const bfv8*)&wqp[kn * 2048];
      bfv8 akn = *(const bfv8*)&wkp[kn * 2048];
#pragma unroll
      for (int nt = 0; nt < 4; nt++) {
        bfv8 bx = ld8(&xs[nt * 16 + l15][kc * 32 + quad * 8]);
        accQ[nt] = __builtin_amdgcn_mfma_f32_16x16x32_bf16(aq, bx, accQ[nt], 0, 0, 0);
        accK[nt] = __builtin_amdgcn_mfma_f32_16x16x32_bf16(ak, bx, accK[nt], 0, 0, 0);
      }
      aq = aqn; ak = akn;
    }
    f4 bq4 = *(const f4*)&bq[w * 16 + quad * 4];
    f4 bk4 = *(const f4*)&bk[w * 16 + quad * 4];
#pragma unroll
    for (int nt = 0; nt < 4; nt++) {
      const size_t orow = ((size_t)(b * N_) + n0 + nt * 16 + l15) * D_ + w * 16 + quad * 4;
      bfv4 pq, pk;
#pragma unroll
      for (int r = 0; r < 4; r++) {
        pq[r] = (__bf16)(accQ[nt][r] + bq4[r]);
        pk[r] = (__bf16)(accK[nt][r] + bk4[r]);
      }
      *(bfv4*)&Qb[orow] = pq;
      *(bfv4*)&Kb[orow] = pk;
    }
  }

  // ---- V: wave w owns c-range w*128; 2-deep Wv fragment pipeline ----
  {
    f16v acc[4][2];
#pragma unroll
    for (int mt = 0; mt < 4; mt++)
#pragma unroll
      for (int nt = 0; nt < 2; nt++) acc[mt][nt] = (f16v)(0.0f);
    // panel base: elem (kc*512 + m)*16 + h*8, m = w*128 + mt*32 + l31
    const u16* wvp[4];
#pragma unroll
    for (int mt = 0; mt < 4; mt++)
      wvp[mt] = &Wvb[(size_t)(w * 128 + mt * 32 + l31) * 16 + h * 8];

    bfv8 acur[4], anxt[4];
#pragma unroll
    for (int mt = 0; mt < 4; mt++) acur[mt] = *(const bfv8*)&wvp[mt][0];

    for (int kc2 = 0; kc2 < 16; kc2++) {
      {
        const int kc = 2 * kc2;
#pragma unroll
        for (int mt = 0; mt < 4; mt++)
          anxt[mt] = *(const bfv8*)&wvp[mt][(size_t)(kc + 1) * 8192];
        bfv8 bx0 = ld8(&xs[l31][kc * 16 + h * 8]);
        bfv8 bx1 = ld8(&xs[32 + l31][kc * 16 + h * 8]);
#pragma unroll
        for (int mt = 0; mt < 4; mt++) {
          acc[mt][0] = __builtin_amdgcn_mfma_f32_32x32x16_bf16(acur[mt], bx0, acc[mt][0], 0, 0, 0);
          acc[mt][1] = __builtin_amdgcn_mfma_f32_32x32x16_bf16(acur[mt], bx1, acc[mt][1], 0, 0, 0);
        }
      }
      {
        const int kc = 2 * kc2 + 1;
        const int kn = (kc + 1) & 31;          // wrap: avoids OOB tail read
#pragma unroll
        for (int mt = 0; mt < 4; mt++)
          acur[mt] = *(const bfv8*)&wvp[mt][(size_t)kn * 8192];
        bfv8 bx0 = ld8(&xs[l31][kc * 16 + h * 8]);
        bfv8 bx1 = ld8(&xs[32 + l31][kc * 16 + h * 8]);
#pragma unroll
        for (int mt = 0; mt < 4; mt++) {
          acc[mt][0] = __builtin_amdgcn_mfma_f32_32x32x16_bf16(anxt[mt], bx0, acc[mt][0], 0, 0, 0);
          acc[mt][1] = __builtin_amdgcn_mfma_f32_32x32x16_bf16(anxt[mt], bx1, acc[mt][1], 0, 0, 0);
        }
      }
    }
#pragma unroll
    for (int mt = 0; mt < 4; mt++)
#pragma unroll
      for (int nt = 0; nt < 2; nt++)
#pragma unroll
        for (int g = 0; g < 4; g++) {
          f4 bv4 = *(const f4*)&bv[w * 128 + mt * 32 + g * 8 + h * 4];
#pragma unroll
          for (int r = 0; r < 4; r++) {
            int c = w * 128 + mt * 32 + g * 8 + h * 4 + r;
            *(__bf16*)&Vb[((size_t)(b * C_) + c) * N_ + n0 + nt * 32 + l31] =
                (__bf16)(acc[mt][nt][g * 4 + r] + bv4[r]);
          }
        }
  }
}

// ---------------- fused attention v2.1 (120 us proven, UNCHANGED) ----------
#define PS_STR 68   // u16: 34 dwords -> 2-way bank pattern (free)

__device__ __forceinline__ void stage_v(const u16* p0, u16* vsw, int j0) {
#pragma unroll
  for (int s = 0; s < 8; s++) {
    __builtin_amdgcn_global_load_lds(
        (const __attribute__((address_space(1))) void*)(p0 + (size_t)s * 8 * N_ + j0),
        (__attribute__((address_space(3))) void*)(vsw + s * 512),
        16, 0, 0);
  }
}

__global__ __launch_bounds__(256, 2) void attn(
    const float* __restrict__ x, const u16* __restrict__ Qb,
    const u16* __restrict__ Kb, const u16* __restrict__ Vb,
    const float* __restrict__ gamma, float* __restrict__ out) {
  __shared__ u16 Vs[4][64][64];        // [wave][c_local][j], swizzled chunks
  __shared__ u16 Ps[2][128][PS_STR];   // [buf][i][j]
  __shared__ float invl[128];
  const int b = blockIdx.x, i0 = blockIdx.y * 128, ch = blockIdx.z;
  const int t = threadIdx.x, w = t >> 6, lane = t & 63;
  const int l15 = lane & 15, quad = lane >> 4;
  const int l31 = lane & 31, h = lane >> 5;

  // V staging geometry: lane = r*8 + xchunk; LDS[row][x] = G[row][x ^ (row&7)]
  const int sr = lane >> 3;            // row within 8-row group
  const int sx = lane & 7;             // chunk slot
  const int cbase = ch * 256 + w * 64; // this wave's c-slice
  const u16* p0 = &Vb[((size_t)(b * C_) + cbase + sr) * N_ + ((sx ^ sr) << 3)];
  u16* vsw = &Vs[w][0][0];

  stage_v(p0, vsw, 0);                 // prefetch first V tile (async)

  bfv8 qf[2][2];                       // [isub][kc]
#pragma unroll
  for (int isub = 0; isub < 2; isub++)
#pragma unroll
    for (int kc = 0; kc < 2; kc++)
      qf[isub][kc] = *(const bfv8*)&Qb[((size_t)(b * N_) + i0 + w * 32 + isub * 16 + l15) * D_ +
                                       kc * 32 + quad * 8];

  f16v acc[4][2];   // mt: i = mt*32.., nt: c = cbase + nt*32..
#pragma unroll
  for (int mt = 0; mt < 4; mt++)
#pragma unroll
    for (int nt = 0; nt < 2; nt++) acc[mt][nt] = (f16v)(0.0f);
  float la0 = 0.0f, la1 = 0.0f;
  const int swz = l31 & 7;

  int buf = 0;
  for (int j0 = 0; j0 < N_; j0 += 64, buf ^= 1) {
    // ---- E^T: wave w computes cols i = w*32..+32 (2 subtiles), all 64 j ----
#pragma unroll
    for (int jt = 0; jt < 4; jt++) {
      const u16* krow = &Kb[((size_t)(b * N_) + j0 + jt * 16 + l15) * D_];
      bfv8 kf0 = *(const bfv8*)&krow[quad * 8];
      bfv8 kf1 = *(const bfv8*)&krow[32 + quad * 8];
      f4 e0 = (f4)(0.0f), e1 = (f4)(0.0f);
      e0 = __builtin_amdgcn_mfma_f32_16x16x32_bf16(kf0, qf[0][0], e0, 0, 0, 0);
      e0 = __builtin_amdgcn_mfma_f32_16x16x32_bf16(kf1, qf[0][1], e0, 0, 0, 0);
      e1 = __builtin_amdgcn_mfma_f32_16x16x32_bf16(kf0, qf[1][0], e1, 0, 0, 0);
      e1 = __builtin_amdgcn_mfma_f32_16x16x32_bf16(kf1, qf[1][1], e1, 0, 0, 0);
      {
        float p0_ = __expf(e0[0]), p1_ = __expf(e0[1]);
        float p2_ = __expf(e0[2]), p3_ = __expf(e0[3]);
        la0 += (p0_ + p1_) + (p2_ + p3_);
        bfv4 pk;
        pk[0] = (__bf16)p0_; pk[1] = (__bf16)p1_;
        pk[2] = (__bf16)p2_; pk[3] = (__bf16)p3_;
        *(bfv4*)&Ps[buf][w * 32 + l15][jt * 16 + quad * 4] = pk;
      }
      {
        float p0_ = __expf(e1[0]), p1_ = __expf(e1[1]);
        float p2_ = __expf(e1[2]), p3_ = __expf(e1[3]);
        la1 += (p0_ + p1_) + (p2_ + p3_);
        bfv4 pk;
        pk[0] = (__bf16)p0_; pk[1] = (__bf16)p1_;
        pk[2] = (__bf16)p2_; pk[3] = (__bf16)p3_;
        *(bfv4*)&Ps[buf][w * 32 + 16 + l15][jt * 16 + quad * 4] = pk;
      }
    }
    // barrier: Ps[buf] published; implicit vmcnt(0) drain completes V stage
    __syncthreads();

    // ---- PV: A = P (LDS, all 128 i), B = V (LDS, own 64-c slice) ----
    __builtin_amdgcn_s_setprio(1);
#pragma unroll
    for (int kc = 0; kc < 4; kc++) {
      bfv8 pa[4];
#pragma unroll
      for (int mt = 0; mt < 4; mt++)
        pa[mt] = ld8(&Ps[buf][mt * 32 + l31][kc * 16 + h * 8]);
      bfv8 vb[2];
#pragma unroll
      for (int nt = 0; nt < 2; nt++)
        vb[nt] = *(const bfv8*)&vsw[(nt * 32 + l31) * 64 + (((kc * 2 + h) ^ swz) << 3)];
#pragma unroll
      for (int mt = 0; mt < 4; mt++)
#pragma unroll
        for (int nt = 0; nt < 2; nt++)
          acc[mt][nt] = __builtin_amdgcn_mfma_f32_32x32x16_bf16(pa[mt], vb[nt], acc[mt][nt], 0, 0, 0);
    }
    __builtin_amdgcn_s_setprio(0);
    // pin: stage must not be hoisted above the Vs ds_reads it overwrites
    __builtin_amdgcn_sched_barrier(0);
    if (j0 + 64 < N_) stage_v(p0, vsw, j0 + 64);   // async prefetch next tile
  }

  la0 += __shfl_xor(la0, 16, 64);
  la0 += __shfl_xor(la0, 32, 64);
  la1 += __shfl_xor(la1, 16, 64);
  la1 += __shfl_xor(la1, 32, 64);
  if (lane < 16) {
    invl[w * 32 + l15]      = 1.0f / la0;
    invl[w * 32 + 16 + l15] = 1.0f / la1;
  }
  __syncthreads();

  const float gam = gamma[0];
#pragma unroll
  for (int mt = 0; mt < 4; mt++)
#pragma unroll
    for (int nt = 0; nt < 2; nt++) {
      int c = cbase + nt * 32 + l31;
#pragma unroll
      for (int g = 0; g < 4; g++) {
        int ib = mt * 32 + g * 8 + h * 4;
        f4 il = *(const f4*)&invl[ib];
        size_t off = ((size_t)(b * C_) + c) * N_ + i0 + ib;
        f4 xv = *(const f4*)&x[off];
        f4 o;
#pragma unroll
        for (int r = 0; r < 4; r++)
          o[r] = xv[r] + gam * acc[mt][nt][g * 4 + r] * il[r];
        *(f4*)&out[off] = o;
      }
    }
}

extern "C" void kernel_launch(void* const* d_in, const int* in_sizes, int n_in,
                              void* d_out, int out_size, void* d_ws, size_t ws_size,
                              hipStream_t stream) {
  const float* x     = (const float*)d_in[0];
  const float* Wq    = (const float*)d_in[1];
  const float* bq    = (const float*)d_in[2];
  const float* Wk    = (const float*)d_in[3];
  const float* bk    = (const float*)d_in[4];
  const float* Wv    = (const float*)d_in[5];
  const float* bv    = (const float*)d_in[6];
  const float* gamma = (const float*)d_in[7];
  float* out = (float*)d_out;

  u16* wsu = (u16*)d_ws;
  u16* Qb  = wsu;                                   // B*N*D
  u16* Kb  = Qb  + (size_t)B_ * N_ * D_;            // B*N*D
  u16* Vb  = Kb  + (size_t)B_ * N_ * D_;            // B*C*N
  u16* Wqb = Vb  + (size_t)B_ * C_ * N_;            // D*C (panelized)
  u16* Wkb = Wqb + (size_t)D_ * C_;                 // D*C (panelized)
  u16* Wvb = Wkb + (size_t)D_ * C_;                 // C*C (panelized)

  conv_all<<<dim3(320), 256, 0, stream>>>(Wq, Wk, Wv, Wqb, Wkb, Wvb);
  proj_all<<<dim3(B_, N_ / 64), 256, 0, stream>>>(x, Wqb, Wkb, bq, bk, Wvb, bv, Qb, Kb, Vb);
  attn<<<dim3(B_, N_ / 128, 2), 256, 0, stream>>>(x, Qb, Kb, Vb, gamma, out);
}

// Round 9
// 246.503 us; speedup vs baseline: 1.3715x; 1.0327x over previous
//
#include <hip/hip_runtime.h>

#define B_ 16
#define C_ 512
#define N_ 2048
#define D_ 64

typedef unsigned short u16;
typedef unsigned int   u32;
typedef __bf16 bfv2 __attribute__((ext_vector_type(2)));
typedef __bf16 bfv4 __attribute__((ext_vector_type(4)));
typedef __bf16 bfv8 __attribute__((ext_vector_type(8)));
typedef float  f4   __attribute__((ext_vector_type(4)));
typedef float  f16v __attribute__((ext_vector_type(16)));

// 8-byte-aligned LDS load of 8 bf16 (2 x ds_read_b64)
__device__ __forceinline__ bfv8 ld8(const u16* p) {
  bfv4 lo = *(const bfv4*)p;
  bfv4 hi = *(const bfv4*)(p + 4);
  bfv8 r;
  r[0] = lo[0]; r[1] = lo[1]; r[2] = lo[2]; r[3] = lo[3];
  r[4] = hi[0]; r[5] = hi[1]; r[6] = hi[2]; r[7] = hi[3];
  return r;
}

// ---------------- all W -> bf16 + K-PANEL layout, one launch ----------------
// Wq/Wk: element (d, c) -> Wqp[((c>>5)*64 + d)*32 + (c&31)]
// Wv:    element (m, c) -> Wvp[((c>>4)*512 + m)*16 + (c&15)]
__global__ __launch_bounds__(256) void conv_all(
    const float* __restrict__ Wq, const float* __restrict__ Wk,
    const float* __restrict__ Wv,
    u16* __restrict__ Wqb, u16* __restrict__ Wkb, u16* __restrict__ Wvb) {
  const int q4 = D_ * C_ / 4;   // 8192
  const int v4 = C_ * C_ / 4;   // 65536
  int i = blockIdx.x * 256 + threadIdx.x;
  const float* src; u16* dst; int j; int isv;
  if (i < q4)            { src = Wq; dst = Wqb; j = i; isv = 0; }
  else if (i < 2 * q4)   { src = Wk; dst = Wkb; j = i - q4; isv = 0; }
  else                   { j = i - 2 * q4; if (j >= v4) return; src = Wv; dst = Wvb; isv = 1; }
  float4 v = ((const float4*)src)[j];
  bfv4 o;
  o[0] = (__bf16)v.x; o[1] = (__bf16)v.y;
  o[2] = (__bf16)v.z; o[3] = (__bf16)v.w;
  size_t d;
  if (isv) {
    const int m = j >> 7, ci = (j & 127) * 4;          // Wv: 512 rows, C=512
    d = ((size_t)(ci >> 4) * 512 + m) * 16 + (ci & 15);
  } else {
    const int dd = j >> 7, ci = (j & 127) * 4;         // Wq/Wk: 64 rows, C=512
    d = ((size_t)(ci >> 5) * 64 + dd) * 32 + (ci & 31);
  }
  *(bfv4*)&dst[d] = o;
}

// ---------------- fused transpose + Q/K/V projection v4 ----------------
// 512 threads (8 waves): same 64.5 KB xs -> 2 blocks/CU -> 16 waves/CU
// (was 8). Per-wave state halved to fit 4 waves/SIMD at <=128 VGPR:
//   QK: wave w -> d-slice (w&3)*16, n-half (w>>2)*32 (acc 16 regs)
//   V : wave w -> c-range w*64 (acc[2][2] = 64 regs)
// Work per block unchanged; weight reads duplicate 2x in L2 (cheap).
#define XS_STR 516   // u16 row stride
__global__ __launch_bounds__(512, 4) void proj_all(
    const float* __restrict__ x,
    const u16* __restrict__ Wqb, const u16* __restrict__ Wkb,
    const float* __restrict__ bq, const float* __restrict__ bk,
    const u16* __restrict__ Wvb, const float* __restrict__ bv,
    u16* __restrict__ Qb, u16* __restrict__ Kb, u16* __restrict__ Vb) {
  __shared__ u16 xs[64][XS_STR];    // [n][c] 64.5 KB
  const int b = blockIdx.x, n0 = blockIdx.y * 64;
  const int t = threadIdx.x;
  const int w = t >> 6, lane = t & 63;
  const int l15 = lane & 15, quad = lane >> 4;
  const int l31 = lane & 31, h = lane >> 5;

  // ---- stage + transpose: 8 passes x (16 n-float4 x 32 c-pairs) ----
  {
    const int n4 = t & 15, cp = t >> 4;   // cp in [0,32)
#pragma unroll 4
    for (int p = 0; p < 8; p++) {
      int c = p * 64 + cp * 2;
      const size_t rb = ((size_t)(b * C_) + c) * N_ + n0 + n4 * 4;
      float4 a = *(const float4*)&x[rb];
      float4 bb = *(const float4*)&x[rb + N_];
      bfv2 w0, w1, w2, w3;
      w0[0] = (__bf16)a.x; w0[1] = (__bf16)bb.x;
      w1[0] = (__bf16)a.y; w1[1] = (__bf16)bb.y;
      w2[0] = (__bf16)a.z; w2[1] = (__bf16)bb.z;
      w3[0] = (__bf16)a.w; w3[1] = (__bf16)bb.w;
      *(bfv2*)&xs[n4 * 4 + 0][c] = w0;
      *(bfv2*)&xs[n4 * 4 + 1][c] = w1;
      *(bfv2*)&xs[n4 * 4 + 2][c] = w2;
      *(bfv2*)&xs[n4 * 4 + 3][c] = w3;
    }
  }
  __syncthreads();

  // ---- Q/K: wave w -> d-rows (w&3)*16..+16, n-half (w>>2)*32..+32 ----
  {
    const int dw = (w & 3) * 16, nh = (w >> 2) * 32;
    f4 accQ[2], accK[2];
#pragma unroll
    for (int nt = 0; nt < 2; nt++) { accQ[nt] = (f4)(0.0f); accK[nt] = (f4)(0.0f); }
    // panel base: elem (kc*64 + d)*32 + quad*8, d = dw+l15
    const u16* wqp = &Wqb[(size_t)(dw + l15) * 32 + quad * 8];
    const u16* wkp = &Wkb[(size_t)(dw + l15) * 32 + quad * 8];
    bfv8 aq = *(const bfv8*)&wqp[0];
    bfv8 ak = *(const bfv8*)&wkp[0];
    for (int kc = 0; kc < 16; kc++) {
      const int kn = (kc + 1) & 15;            // wrap: avoids OOB tail read
      bfv8 aqn = *(const bfv8*)&wqp[kn * 2048];
      bfv8 akn = *(const bfv8*)&wkp[kn * 2048];
#pragma unroll
      for (int nt = 0; nt < 2; nt++) {
        bfv8 bx = ld8(&xs[nh + nt * 16 + l15][kc * 32 + quad * 8]);
        accQ[nt] = __builtin_amdgcn_mfma_f32_16x16x32_bf16(aq, bx, accQ[nt], 0, 0, 0);
        accK[nt] = __builtin_amdgcn_mfma_f32_16x16x32_bf16(ak, bx, accK[nt], 0, 0, 0);
      }
      aq = aqn; ak = akn;
    }
    f4 bq4 = *(const f4*)&bq[dw + quad * 4];
    f4 bk4 = *(const f4*)&bk[dw + quad * 4];
#pragma unroll
    for (int nt = 0; nt < 2; nt++) {
      const size_t orow = ((size_t)(b * N_) + n0 + nh + nt * 16 + l15) * D_ + dw + quad * 4;
      bfv4 pq, pk;
#pragma unroll
      for (int r = 0; r < 4; r++) {
        pq[r] = (__bf16)(accQ[nt][r] + bq4[r]);
        pk[r] = (__bf16)(accK[nt][r] + bk4[r]);
      }
      *(bfv4*)&Qb[orow] = pq;
      *(bfv4*)&Kb[orow] = pk;
    }
  }

  // ---- V: wave w owns c-range w*64; 2-deep Wv fragment pipeline ----
  {
    f16v acc[2][2];
#pragma unroll
    for (int mt = 0; mt < 2; mt++)
#pragma unroll
      for (int nt = 0; nt < 2; nt++) acc[mt][nt] = (f16v)(0.0f);
    // panel base: elem (kc*512 + m)*16 + h*8, m = w*64 + mt*32 + l31
    const u16* wvp[2];
#pragma unroll
    for (int mt = 0; mt < 2; mt++)
      wvp[mt] = &Wvb[(size_t)(w * 64 + mt * 32 + l31) * 16 + h * 8];

    bfv8 acur[2], anxt[2];
#pragma unroll
    for (int mt = 0; mt < 2; mt++) acur[mt] = *(const bfv8*)&wvp[mt][0];

    for (int kc2 = 0; kc2 < 16; kc2++) {
      {
        const int kc = 2 * kc2;
#pragma unroll
        for (int mt = 0; mt < 2; mt++)
          anxt[mt] = *(const bfv8*)&wvp[mt][(size_t)(kc + 1) * 8192];
        bfv8 bx0 = ld8(&xs[l31][kc * 16 + h * 8]);
        bfv8 bx1 = ld8(&xs[32 + l31][kc * 16 + h * 8]);
#pragma unroll
        for (int mt = 0; mt < 2; mt++) {
          acc[mt][0] = __builtin_amdgcn_mfma_f32_32x32x16_bf16(acur[mt], bx0, acc[mt][0], 0, 0, 0);
          acc[mt][1] = __builtin_amdgcn_mfma_f32_32x32x16_bf16(acur[mt], bx1, acc[mt][1], 0, 0, 0);
        }
      }
      {
        const int kc = 2 * kc2 + 1;
        const int kn = (kc + 1) & 31;          // wrap: avoids OOB tail read
#pragma unroll
        for (int mt = 0; mt < 2; mt++)
          acur[mt] = *(const bfv8*)&wvp[mt][(size_t)kn * 8192];
        bfv8 bx0 = ld8(&xs[l31][kc * 16 + h * 8]);
        bfv8 bx1 = ld8(&xs[32 + l31][kc * 16 + h * 8]);
#pragma unroll
        for (int mt = 0; mt < 2; mt++) {
          acc[mt][0] = __builtin_amdgcn_mfma_f32_32x32x16_bf16(anxt[mt], bx0, acc[mt][0], 0, 0, 0);
          acc[mt][1] = __builtin_amdgcn_mfma_f32_32x32x16_bf16(anxt[mt], bx1, acc[mt][1], 0, 0, 0);
        }
      }
    }
#pragma unroll
    for (int mt = 0; mt < 2; mt++)
#pragma unroll
      for (int nt = 0; nt < 2; nt++)
#pragma unroll
        for (int g = 0; g < 4; g++) {
          f4 bv4 = *(const f4*)&bv[w * 64 + mt * 32 + g * 8 + h * 4];
#pragma unroll
          for (int r = 0; r < 4; r++) {
            int c = w * 64 + mt * 32 + g * 8 + h * 4 + r;
            *(__bf16*)&Vb[((size_t)(b * C_) + c) * N_ + n0 + nt * 32 + l31] =
                (__bf16)(acc[mt][nt][g * 4 + r] + bv4[r]);
          }
        }
  }
}

// ---------------- fused attention v2.1 (122.8 us proven, UNCHANGED) --------
#define PS_STR 68   // u16: 34 dwords -> 2-way bank pattern (free)

__device__ __forceinline__ void stage_v(const u16* p0, u16* vsw, int j0) {
#pragma unroll
  for (int s = 0; s < 8; s++) {
    __builtin_amdgcn_global_load_lds(
        (const __attribute__((address_space(1))) void*)(p0 + (size_t)s * 8 * N_ + j0),
        (__attribute__((address_space(3))) void*)(vsw + s * 512),
        16, 0, 0);
  }
}

__global__ __launch_bounds__(256, 2) void attn(
    const float* __restrict__ x, const u16* __restrict__ Qb,
    const u16* __restrict__ Kb, const u16* __restrict__ Vb,
    const float* __restrict__ gamma, float* __restrict__ out) {
  __shared__ u16 Vs[4][64][64];        // [wave][c_local][j], swizzled chunks
  __shared__ u16 Ps[2][128][PS_STR];   // [buf][i][j]
  __shared__ float invl[128];
  const int b = blockIdx.x, i0 = blockIdx.y * 128, ch = blockIdx.z;
  const int t = threadIdx.x, w = t >> 6, lane = t & 63;
  const int l15 = lane & 15, quad = lane >> 4;
  const int l31 = lane & 31, h = lane >> 5;

  // V staging geometry: lane = r*8 + xchunk; LDS[row][x] = G[row][x ^ (row&7)]
  const int sr = lane >> 3;            // row within 8-row group
  const int sx = lane & 7;             // chunk slot
  const int cbase = ch * 256 + w * 64; // this wave's c-slice
  const u16* p0 = &Vb[((size_t)(b * C_) + cbase + sr) * N_ + ((sx ^ sr) << 3)];
  u16* vsw = &Vs[w][0][0];

  stage_v(p0, vsw, 0);                 // prefetch first V tile (async)

  bfv8 qf[2][2];                       // [isub][kc]
#pragma unroll
  for (int isub = 0; isub < 2; isub++)
#pragma unroll
    for (int kc = 0; kc < 2; kc++)
      qf[isub][kc] = *(const bfv8*)&Qb[((size_t)(b * N_) + i0 + w * 32 + isub * 16 + l15) * D_ +
                                       kc * 32 + quad * 8];

  f16v acc[4][2];   // mt: i = mt*32.., nt: c = cbase + nt*32..
#pragma unroll
  for (int mt = 0; mt < 4; mt++)
#pragma unroll
    for (int nt = 0; nt < 2; nt++) acc[mt][nt] = (f16v)(0.0f);
  float la0 = 0.0f, la1 = 0.0f;
  const int swz = l31 & 7;

  int buf = 0;
  for (int j0 = 0; j0 < N_; j0 += 64, buf ^= 1) {
    // ---- E^T: wave w computes cols i = w*32..+32 (2 subtiles), all 64 j ----
#pragma unroll
    for (int jt = 0; jt < 4; jt++) {
      const u16* krow = &Kb[((size_t)(b * N_) + j0 + jt * 16 + l15) * D_];
      bfv8 kf0 = *(const bfv8*)&krow[quad * 8];
      bfv8 kf1 = *(const bfv8*)&krow[32 + quad * 8];
      f4 e0 = (f4)(0.0f), e1 = (f4)(0.0f);
      e0 = __builtin_amdgcn_mfma_f32_16x16x32_bf16(kf0, qf[0][0], e0, 0, 0, 0);
      e0 = __builtin_amdgcn_mfma_f32_16x16x32_bf16(kf1, qf[0][1], e0, 0, 0, 0);
      e1 = __builtin_amdgcn_mfma_f32_16x16x32_bf16(kf0, qf[1][0], e1, 0, 0, 0);
      e1 = __builtin_amdgcn_mfma_f32_16x16x32_bf16(kf1, qf[1][1], e1, 0, 0, 0);
      {
        float p0_ = __expf(e0[0]), p1_ = __expf(e0[1]);
        float p2_ = __expf(e0[2]), p3_ = __expf(e0[3]);
        la0 += (p0_ + p1_) + (p2_ + p3_);
        bfv4 pk;
        pk[0] = (__bf16)p0_; pk[1] = (__bf16)p1_;
        pk[2] = (__bf16)p2_; pk[3] = (__bf16)p3_;
        *(bfv4*)&Ps[buf][w * 32 + l15][jt * 16 + quad * 4] = pk;
      }
      {
        float p0_ = __expf(e1[0]), p1_ = __expf(e1[1]);
        float p2_ = __expf(e1[2]), p3_ = __expf(e1[3]);
        la1 += (p0_ + p1_) + (p2_ + p3_);
        bfv4 pk;
        pk[0] = (__bf16)p0_; pk[1] = (__bf16)p1_;
        pk[2] = (__bf16)p2_; pk[3] = (__bf16)p3_;
        *(bfv4*)&Ps[buf][w * 32 + 16 + l15][jt * 16 + quad * 4] = pk;
      }
    }
    // barrier: Ps[buf] published; implicit vmcnt(0) drain completes V stage
    __syncthreads();

    // ---- PV: A = P (LDS, all 128 i), B = V (LDS, own 64-c slice) ----
    __builtin_amdgcn_s_setprio(1);
#pragma unroll
    for (int kc = 0; kc < 4; kc++) {
      bfv8 pa[4];
#pragma unroll
      for (int mt = 0; mt < 4; mt++)
        pa[mt] = ld8(&Ps[buf][mt * 32 + l31][kc * 16 + h * 8]);
      bfv8 vb[2];
#pragma unroll
      for (int nt = 0; nt < 2; nt++)
        vb[nt] = *(const bfv8*)&vsw[(nt * 32 + l31) * 64 + (((kc * 2 + h) ^ swz) << 3)];
#pragma unroll
      for (int mt = 0; mt < 4; mt++)
#pragma unroll
        for (int nt = 0; nt < 2; nt++)
          acc[mt][nt] = __builtin_amdgcn_mfma_f32_32x32x16_bf16(pa[mt], vb[nt], acc[mt][nt], 0, 0, 0);
    }
    __builtin_amdgcn_s_setprio(0);
    // pin: stage must not be hoisted above the Vs ds_reads it overwrites
    __builtin_amdgcn_sched_barrier(0);
    if (j0 + 64 < N_) stage_v(p0, vsw, j0 + 64);   // async prefetch next tile
  }

  la0 += __shfl_xor(la0, 16, 64);
  la0 += __shfl_xor(la0, 32, 64);
  la1 += __shfl_xor(la1, 16, 64);
  la1 += __shfl_xor(la1, 32, 64);
  if (lane < 16) {
    invl[w * 32 + l15]      = 1.0f / la0;
    invl[w * 32 + 16 + l15] = 1.0f / la1;
  }
  __syncthreads();

  const float gam = gamma[0];
#pragma unroll
  for (int mt = 0; mt < 4; mt++)
#pragma unroll
    for (int nt = 0; nt < 2; nt++) {
      int c = cbase + nt * 32 + l31;
#pragma unroll
      for (int g = 0; g < 4; g++) {
        int ib = mt * 32 + g * 8 + h * 4;
        f4 il = *(const f4*)&invl[ib];
        size_t off = ((size_t)(b * C_) + c) * N_ + i0 + ib;
        f4 xv = *(const f4*)&x[off];
        f4 o;
#pragma unroll
        for (int r = 0; r < 4; r++)
          o[r] = xv[r] + gam * acc[mt][nt][g * 4 + r] * il[r];
        *(f4*)&out[off] = o;
      }
    }
}

extern "C" void kernel_launch(void* const* d_in, const int* in_sizes, int n_in,
                              void* d_out, int out_size, void* d_ws, size_t ws_size,
                              hipStream_t stream) {
  const float* x     = (const float*)d_in[0];
  const float* Wq    = (const float*)d_in[1];
  const float* bq    = (const float*)d_in[2];
  const float* Wk    = (const float*)d_in[3];
  const float* bk    = (const float*)d_in[4];
  const float* Wv    = (const float*)d_in[5];
  const float* bv    = (const float*)d_in[6];
  const float* gamma = (const float*)d_in[7];
  float* out = (float*)d_out;

  u16* wsu = (u16*)d_ws;
  u16* Qb  = wsu;                                   // B*N*D
  u16* Kb  = Qb  + (size_t)B_ * N_ * D_;            // B*N*D
  u16* Vb  = Kb  + (size_t)B_ * N_ * D_;            // B*C*N
  u16* Wqb = Vb  + (size_t)B_ * C_ * N_;            // D*C (panelized)
  u16* Wkb = Wqb + (size_t)D_ * C_;                 // D*C (panelized)
  u16* Wvb = Wkb + (size_t)D_ * C_;                 // C*C (panelized)

  conv_all<<<dim3(320), 256, 0, stream>>>(Wq, Wk, Wv, Wqb, Wkb, Wvb);
  proj_all<<<dim3(B_, N_ / 64), 512, 0, stream>>>(x, Wqb, Wkb, bq, bk, Wvb, bv, Qb, Kb, Vb);
  attn<<<dim3(B_, N_ / 128, 2), 256, 0, stream>>>(x, Qb, Kb, Vb, gamma, out);
}

// Round 10
// 244.406 us; speedup vs baseline: 1.3833x; 1.0086x over previous
//
#include <hip/hip_runtime.h>

#define B_ 16
#define C_ 512
#define N_ 2048
#define D_ 64

typedef unsigned short u16;
typedef unsigned int   u32;
typedef __bf16 bfv2 __attribute__((ext_vector_type(2)));
typedef __bf16 bfv4 __attribute__((ext_vector_type(4)));
typedef __bf16 bfv8 __attribute__((ext_vector_type(8)));
typedef float  f4   __attribute__((ext_vector_type(4)));
typedef float  f16v __attribute__((ext_vector_type(16)));

// 8-byte-aligned LDS load of 8 bf16 (2 x ds_read_b64)
__device__ __forceinline__ bfv8 ld8(const u16* p) {
  bfv4 lo = *(const bfv4*)p;
  bfv4 hi = *(const bfv4*)(p + 4);
  bfv8 r;
  r[0] = lo[0]; r[1] = lo[1]; r[2] = lo[2]; r[3] = lo[3];
  r[4] = hi[0]; r[5] = hi[1]; r[6] = hi[2]; r[7] = hi[3];
  return r;
}

// ---------------- all W -> bf16 + K-PANEL layout, one launch ----------------
// Wq/Wk: element (d, c) -> Wqp[((c>>5)*64 + d)*32 + (c&31)]
// Wv:    element (m, c) -> Wvp[((c>>4)*512 + m)*16 + (c&15)]
__global__ __launch_bounds__(256) void conv_all(
    const float* __restrict__ Wq, const float* __restrict__ Wk,
    const float* __restrict__ Wv,
    u16* __restrict__ Wqb, u16* __restrict__ Wkb, u16* __restrict__ Wvb) {
  const int q4 = D_ * C_ / 4;   // 8192
  const int v4 = C_ * C_ / 4;   // 65536
  int i = blockIdx.x * 256 + threadIdx.x;
  const float* src; u16* dst; int j; int isv;
  if (i < q4)            { src = Wq; dst = Wqb; j = i; isv = 0; }
  else if (i < 2 * q4)   { src = Wk; dst = Wkb; j = i - q4; isv = 0; }
  else                   { j = i - 2 * q4; if (j >= v4) return; src = Wv; dst = Wvb; isv = 1; }
  float4 v = ((const float4*)src)[j];
  bfv4 o;
  o[0] = (__bf16)v.x; o[1] = (__bf16)v.y;
  o[2] = (__bf16)v.z; o[3] = (__bf16)v.w;
  size_t d;
  if (isv) {
    const int m = j >> 7, ci = (j & 127) * 4;          // Wv: 512 rows, C=512
    d = ((size_t)(ci >> 4) * 512 + m) * 16 + (ci & 15);
  } else {
    const int dd = j >> 7, ci = (j & 127) * 4;         // Wq/Wk: 64 rows, C=512
    d = ((size_t)(ci >> 5) * 64 + dd) * 32 + (ci & 31);
  }
  *(bfv4*)&dst[d] = o;
}

// ---------------- fused transpose + Q/K/V projection v4 (unchanged) --------
#define XS_STR 516   // u16 row stride
__global__ __launch_bounds__(512, 4) void proj_all(
    const float* __restrict__ x,
    const u16* __restrict__ Wqb, const u16* __restrict__ Wkb,
    const float* __restrict__ bq, const float* __restrict__ bk,
    const u16* __restrict__ Wvb, const float* __restrict__ bv,
    u16* __restrict__ Qb, u16* __restrict__ Kb, u16* __restrict__ Vb) {
  __shared__ u16 xs[64][XS_STR];    // [n][c] 64.5 KB
  const int b = blockIdx.x, n0 = blockIdx.y * 64;
  const int t = threadIdx.x;
  const int w = t >> 6, lane = t & 63;
  const int l15 = lane & 15, quad = lane >> 4;
  const int l31 = lane & 31, h = lane >> 5;

  // ---- stage + transpose: 8 passes x (16 n-float4 x 32 c-pairs) ----
  {
    const int n4 = t & 15, cp = t >> 4;   // cp in [0,32)
#pragma unroll 4
    for (int p = 0; p < 8; p++) {
      int c = p * 64 + cp * 2;
      const size_t rb = ((size_t)(b * C_) + c) * N_ + n0 + n4 * 4;
      float4 a = *(const float4*)&x[rb];
      float4 bb = *(const float4*)&x[rb + N_];
      bfv2 w0, w1, w2, w3;
      w0[0] = (__bf16)a.x; w0[1] = (__bf16)bb.x;
      w1[0] = (__bf16)a.y; w1[1] = (__bf16)bb.y;
      w2[0] = (__bf16)a.z; w2[1] = (__bf16)bb.z;
      w3[0] = (__bf16)a.w; w3[1] = (__bf16)bb.w;
      *(bfv2*)&xs[n4 * 4 + 0][c] = w0;
      *(bfv2*)&xs[n4 * 4 + 1][c] = w1;
      *(bfv2*)&xs[n4 * 4 + 2][c] = w2;
      *(bfv2*)&xs[n4 * 4 + 3][c] = w3;
    }
  }
  __syncthreads();

  // ---- Q/K: wave w -> d-rows (w&3)*16..+16, n-half (w>>2)*32..+32 ----
  {
    const int dw = (w & 3) * 16, nh = (w >> 2) * 32;
    f4 accQ[2], accK[2];
#pragma unroll
    for (int nt = 0; nt < 2; nt++) { accQ[nt] = (f4)(0.0f); accK[nt] = (f4)(0.0f); }
    const u16* wqp = &Wqb[(size_t)(dw + l15) * 32 + quad * 8];
    const u16* wkp = &Wkb[(size_t)(dw + l15) * 32 + quad * 8];
    bfv8 aq = *(const bfv8*)&wqp[0];
    bfv8 ak = *(const bfv8*)&wkp[0];
    for (int kc = 0; kc < 16; kc++) {
      const int kn = (kc + 1) & 15;            // wrap: avoids OOB tail read
      bfv8 aqn = *(const bfv8*)&wqp[kn * 2048];
      bfv8 akn = *(const bfv8*)&wkp[kn * 2048];
#pragma unroll
      for (int nt = 0; nt < 2; nt++) {
        bfv8 bx = ld8(&xs[nh + nt * 16 + l15][kc * 32 + quad * 8]);
        accQ[nt] = __builtin_amdgcn_mfma_f32_16x16x32_bf16(aq, bx, accQ[nt], 0, 0, 0);
        accK[nt] = __builtin_amdgcn_mfma_f32_16x16x32_bf16(ak, bx, accK[nt], 0, 0, 0);
      }
      aq = aqn; ak = akn;
    }
    f4 bq4 = *(const f4*)&bq[dw + quad * 4];
    f4 bk4 = *(const f4*)&bk[dw + quad * 4];
#pragma unroll
    for (int nt = 0; nt < 2; nt++) {
      const size_t orow = ((size_t)(b * N_) + n0 + nh + nt * 16 + l15) * D_ + dw + quad * 4;
      bfv4 pq, pk;
#pragma unroll
      for (int r = 0; r < 4; r++) {
        pq[r] = (__bf16)(accQ[nt][r] + bq4[r]);
        pk[r] = (__bf16)(accK[nt][r] + bk4[r]);
      }
      *(bfv4*)&Qb[orow] = pq;
      *(bfv4*)&Kb[orow] = pk;
    }
  }

  // ---- V: wave w owns c-range w*64; 2-deep Wv fragment pipeline ----
  {
    f16v acc[2][2];
#pragma unroll
    for (int mt = 0; mt < 2; mt++)
#pragma unroll
      for (int nt = 0; nt < 2; nt++) acc[mt][nt] = (f16v)(0.0f);
    const u16* wvp[2];
#pragma unroll
    for (int mt = 0; mt < 2; mt++)
      wvp[mt] = &Wvb[(size_t)(w * 64 + mt * 32 + l31) * 16 + h * 8];

    bfv8 acur[2], anxt[2];
#pragma unroll
    for (int mt = 0; mt < 2; mt++) acur[mt] = *(const bfv8*)&wvp[mt][0];

    for (int kc2 = 0; kc2 < 16; kc2++) {
      {
        const int kc = 2 * kc2;
#pragma unroll
        for (int mt = 0; mt < 2; mt++)
          anxt[mt] = *(const bfv8*)&wvp[mt][(size_t)(kc + 1) * 8192];
        bfv8 bx0 = ld8(&xs[l31][kc * 16 + h * 8]);
        bfv8 bx1 = ld8(&xs[32 + l31][kc * 16 + h * 8]);
#pragma unroll
        for (int mt = 0; mt < 2; mt++) {
          acc[mt][0] = __builtin_amdgcn_mfma_f32_32x32x16_bf16(acur[mt], bx0, acc[mt][0], 0, 0, 0);
          acc[mt][1] = __builtin_amdgcn_mfma_f32_32x32x16_bf16(acur[mt], bx1, acc[mt][1], 0, 0, 0);
        }
      }
      {
        const int kc = 2 * kc2 + 1;
        const int kn = (kc + 1) & 31;          // wrap: avoids OOB tail read
#pragma unroll
        for (int mt = 0; mt < 2; mt++)
          acur[mt] = *(const bfv8*)&wvp[mt][(size_t)kn * 8192];
        bfv8 bx0 = ld8(&xs[l31][kc * 16 + h * 8]);
        bfv8 bx1 = ld8(&xs[32 + l31][kc * 16 + h * 8]);
#pragma unroll
        for (int mt = 0; mt < 2; mt++) {
          acc[mt][0] = __builtin_amdgcn_mfma_f32_32x32x16_bf16(anxt[mt], bx0, acc[mt][0], 0, 0, 0);
          acc[mt][1] = __builtin_amdgcn_mfma_f32_32x32x16_bf16(anxt[mt], bx1, acc[mt][1], 0, 0, 0);
        }
      }
    }
#pragma unroll
    for (int mt = 0; mt < 2; mt++)
#pragma unroll
      for (int nt = 0; nt < 2; nt++)
#pragma unroll
        for (int g = 0; g < 4; g++) {
          f4 bv4 = *(const f4*)&bv[w * 64 + mt * 32 + g * 8 + h * 4];
#pragma unroll
          for (int r = 0; r < 4; r++) {
            int c = w * 64 + mt * 32 + g * 8 + h * 4 + r;
            *(__bf16*)&Vb[((size_t)(b * C_) + c) * N_ + n0 + nt * 32 + l31] =
                (__bf16)(acc[mt][nt][g * 4 + r] + bv4[r]);
          }
        }
  }
}

// ---------------- fused attention v2.2 ----------------
// v2.1 + K register prefetch across the barrier: next tile's K fragments
// load into kreg at the top of the PV phase (overwriting consumed regs,
// WAR-safe by program order) and get the whole PV+stage phase to complete.
// Removes the 8 cold L2 loads from the E-phase critical path.
// +32 VGPR (~150 total); occupancy unchanged (LDS-capped 2 blocks/CU).
#define PS_STR 68   // u16: 34 dwords -> 2-way bank pattern (free)

__device__ __forceinline__ void stage_v(const u16* p0, u16* vsw, int j0) {
#pragma unroll
  for (int s = 0; s < 8; s++) {
    __builtin_amdgcn_global_load_lds(
        (const __attribute__((address_space(1))) void*)(p0 + (size_t)s * 8 * N_ + j0),
        (__attribute__((address_space(3))) void*)(vsw + s * 512),
        16, 0, 0);
  }
}

__global__ __launch_bounds__(256, 2) void attn(
    const float* __restrict__ x, const u16* __restrict__ Qb,
    const u16* __restrict__ Kb, const u16* __restrict__ Vb,
    const float* __restrict__ gamma, float* __restrict__ out) {
  __shared__ u16 Vs[4][64][64];        // [wave][c_local][j], swizzled chunks
  __shared__ u16 Ps[2][128][PS_STR];   // [buf][i][j]
  __shared__ float invl[128];
  const int b = blockIdx.x, i0 = blockIdx.y * 128, ch = blockIdx.z;
  const int t = threadIdx.x, w = t >> 6, lane = t & 63;
  const int l15 = lane & 15, quad = lane >> 4;
  const int l31 = lane & 31, h = lane >> 5;

  // V staging geometry: lane = r*8 + xchunk; LDS[row][x] = G[row][x ^ (row&7)]
  const int sr = lane >> 3;            // row within 8-row group
  const int sx = lane & 7;             // chunk slot
  const int cbase = ch * 256 + w * 64; // this wave's c-slice
  const u16* p0 = &Vb[((size_t)(b * C_) + cbase + sr) * N_ + ((sx ^ sr) << 3)];
  u16* vsw = &Vs[w][0][0];

  stage_v(p0, vsw, 0);                 // prefetch first V tile (async)

  bfv8 qf[2][2];                       // [isub][kc]
#pragma unroll
  for (int isub = 0; isub < 2; isub++)
#pragma unroll
    for (int kc = 0; kc < 2; kc++)
      qf[isub][kc] = *(const bfv8*)&Qb[((size_t)(b * N_) + i0 + w * 32 + isub * 16 + l15) * D_ +
                                       kc * 32 + quad * 8];

  // K register prefetch buffer: tile j0's fragments, refilled during PV
  const u16* Kbb = &Kb[(size_t)(b * N_) * D_];
  bfv8 kreg[4][2];
#pragma unroll
  for (int jt = 0; jt < 4; jt++) {
    const u16* krow = &Kbb[(size_t)(jt * 16 + l15) * D_];
    kreg[jt][0] = *(const bfv8*)&krow[quad * 8];
    kreg[jt][1] = *(const bfv8*)&krow[32 + quad * 8];
  }

  f16v acc[4][2];   // mt: i = mt*32.., nt: c = cbase + nt*32..
#pragma unroll
  for (int mt = 0; mt < 4; mt++)
#pragma unroll
    for (int nt = 0; nt < 2; nt++) acc[mt][nt] = (f16v)(0.0f);
  float la0 = 0.0f, la1 = 0.0f;
  const int swz = l31 & 7;

  int buf = 0;
  for (int j0 = 0; j0 < N_; j0 += 64, buf ^= 1) {
    // ---- E^T: wave w computes cols i = w*32..+32 (2 subtiles), all 64 j ----
    // K fragments already resident in kreg (prefetched during prev PV).
#pragma unroll
    for (int jt = 0; jt < 4; jt++) {
      f4 e0 = (f4)(0.0f), e1 = (f4)(0.0f);
      e0 = __builtin_amdgcn_mfma_f32_16x16x32_bf16(kreg[jt][0], qf[0][0], e0, 0, 0, 0);
      e0 = __builtin_amdgcn_mfma_f32_16x16x32_bf16(kreg[jt][1], qf[0][1], e0, 0, 0, 0);
      e1 = __builtin_amdgcn_mfma_f32_16x16x32_bf16(kreg[jt][0], qf[1][0], e1, 0, 0, 0);
      e1 = __builtin_amdgcn_mfma_f32_16x16x32_bf16(kreg[jt][1], qf[1][1], e1, 0, 0, 0);
      {
        float p0_ = __expf(e0[0]), p1_ = __expf(e0[1]);
        float p2_ = __expf(e0[2]), p3_ = __expf(e0[3]);
        la0 += (p0_ + p1_) + (p2_ + p3_);
        bfv4 pk;
        pk[0] = (__bf16)p0_; pk[1] = (__bf16)p1_;
        pk[2] = (__bf16)p2_; pk[3] = (__bf16)p3_;
        *(bfv4*)&Ps[buf][w * 32 + l15][jt * 16 + quad * 4] = pk;
      }
      {
        float p0_ = __expf(e1[0]), p1_ = __expf(e1[1]);
        float p2_ = __expf(e1[2]), p3_ = __expf(e1[3]);
        la1 += (p0_ + p1_) + (p2_ + p3_);
        bfv4 pk;
        pk[0] = (__bf16)p0_; pk[1] = (__bf16)p1_;
        pk[2] = (__bf16)p2_; pk[3] = (__bf16)p3_;
        *(bfv4*)&Ps[buf][w * 32 + 16 + l15][jt * 16 + quad * 4] = pk;
      }
    }
    // barrier: Ps[buf] published; implicit vmcnt(0) drain completes V stage
    __syncthreads();

    // ---- PV: A = P (LDS, all 128 i), B = V (LDS, own 64-c slice) ----
    // First: issue next tile's K loads (consumed next E; whole phase to land)
    {
      const int jn = (j0 + 64) & (N_ - 1);     // wrap: harmless in-bounds
#pragma unroll
      for (int jt = 0; jt < 4; jt++) {
        const u16* krow = &Kbb[(size_t)(jn + jt * 16 + l15) * D_];
        kreg[jt][0] = *(const bfv8*)&krow[quad * 8];
        kreg[jt][1] = *(const bfv8*)&krow[32 + quad * 8];
      }
    }
    __builtin_amdgcn_s_setprio(1);
#pragma unroll
    for (int kc = 0; kc < 4; kc++) {
      bfv8 pa[4];
#pragma unroll
      for (int mt = 0; mt < 4; mt++)
        pa[mt] = ld8(&Ps[buf][mt * 32 + l31][kc * 16 + h * 8]);
      bfv8 vb[2];
#pragma unroll
      for (int nt = 0; nt < 2; nt++)
        vb[nt] = *(const bfv8*)&vsw[(nt * 32 + l31) * 64 + (((kc * 2 + h) ^ swz) << 3)];
#pragma unroll
      for (int mt = 0; mt < 4; mt++)
#pragma unroll
        for (int nt = 0; nt < 2; nt++)
          acc[mt][nt] = __builtin_amdgcn_mfma_f32_32x32x16_bf16(pa[mt], vb[nt], acc[mt][nt], 0, 0, 0);
    }
    __builtin_amdgcn_s_setprio(0);
    // pin: stage must not be hoisted above the Vs ds_reads it overwrites
    __builtin_amdgcn_sched_barrier(0);
    if (j0 + 64 < N_) stage_v(p0, vsw, j0 + 64);   // async prefetch next tile
  }

  la0 += __shfl_xor(la0, 16, 64);
  la0 += __shfl_xor(la0, 32, 64);
  la1 += __shfl_xor(la1, 16, 64);
  la1 += __shfl_xor(la1, 32, 64);
  if (lane < 16) {
    invl[w * 32 + l15]      = 1.0f / la0;
    invl[w * 32 + 16 + l15] = 1.0f / la1;
  }
  __syncthreads();

  const float gam = gamma[0];
#pragma unroll
  for (int mt = 0; mt < 4; mt++)
#pragma unroll
    for (int nt = 0; nt < 2; nt++) {
      int c = cbase + nt * 32 + l31;
#pragma unroll
      for (int g = 0; g < 4; g++) {
        int ib = mt * 32 + g * 8 + h * 4;
        f4 il = *(const f4*)&invl[ib];
        size_t off = ((size_t)(b * C_) + c) * N_ + i0 + ib;
        f4 xv = *(const f4*)&x[off];
        f4 o;
#pragma unroll
        for (int r = 0; r < 4; r++)
          o[r] = xv[r] + gam * acc[mt][nt][g * 4 + r] * il[r];
        *(f4*)&out[off] = o;
      }
    }
}

extern "C" void kernel_launch(void* const* d_in, const int* in_sizes, int n_in,
                              void* d_out, int out_size, void* d_ws, size_t ws_size,
                              hipStream_t stream) {
  const float* x     = (const float*)d_in[0];
  const float* Wq    = (const float*)d_in[1];
  const float* bq    = (const float*)d_in[2];
  const float* Wk    = (const float*)d_in[3];
  const float* bk    = (const float*)d_in[4];
  const float* Wv    = (const float*)d_in[5];
  const float* bv    = (const float*)d_in[6];
  const float* gamma = (const float*)d_in[7];
  float* out = (float*)d_out;

  u16* wsu = (u16*)d_ws;
  u16* Qb  = wsu;                                   // B*N*D
  u16* Kb  = Qb  + (size_t)B_ * N_ * D_;            // B*N*D
  u16* Vb  = Kb  + (size_t)B_ * N_ * D_;            // B*C*N
  u16* Wqb = Vb  + (size_t)B_ * C_ * N_;            // D*C (panelized)
  u16* Wkb = Wqb + (size_t)D_ * C_;                 // D*C (panelized)
  u16* Wvb = Wkb + (size_t)D_ * C_;                 // C*C (panelized)

  conv_all<<<dim3(320), 256, 0, stream>>>(Wq, Wk, Wv, Wqb, Wkb, Wvb);
  proj_all<<<dim3(B_, N_ / 64), 512, 0, stream>>>(x, Wqb, Wkb, bq, bk, Wvb, bv, Qb, Kb, Vb);
  attn<<<dim3(B_, N_ / 128, 2), 256, 0, stream>>>(x, Qb, Kb, Vb, gamma, out);
}